// Round 6
// baseline (169.527 us; speedup 1.0000x reference)
//
#include <hip/hip_runtime.h>

// KnowledgeEmbedding loss as 8 fused fp32 GEMMs (M=4096, N=256, K=100) with
// softplus-sum epilogue and fused positive term.
// score(row,neg) = dot(head[h_row]+rvec, tail[neg]) + bias[t_row]
// loss = (1/B) * sum_rel [ sum_row softplus(-pos_row) + sum_{row,neg} softplus(score) ]
//
// Block = 64 rows x 128 negs, K chunked 5x20, SINGLE-buffered LDS (2 barriers
// per chunk). Thread tile 4 rows x 8 negs.
// HISTORY:
//  - dbuf + cross-barrier prefetch regs (R3/R4): peak-live ~100 VGPR vs 64-step
//    allocator -> 3.5 KB/thread scratch spill (WRITE 921 MB, 465 us). AVOID.
//  - single buffer keeps peak-live <= 64 VGPR: no spill at (256,2) [R5] or
//    (256,4) [R2]. (256,2) caps residency at 2 blocks/CU -> Occ 29%,
//    VALUBusy 35%, 43.5 us [R5]. This round: (256,4) for 4 blocks/CU.

#define EMBED   100
#define BATCH   4096
#define NUM_NEG 256
#define KC      20
#define BM      64
#define BN      128
#define NCHUNK  5

struct RelP {
    const float* head;
    const float* tail;
    const float* bias;
    int hc, tc;
};

struct Params {
    RelP rel[8];
    const float* rel_vecs;
    const int*   batch_idxs;
    const int*   neg_idxs;
    float*       out;
};

__device__ __forceinline__ float softplus_f(float x) {
    float e = __expf(-fabsf(x));
    return fmaxf(x, 0.0f) + __logf(1.0f + e);
}

__device__ __forceinline__ float4 fma4(float a, float4 b, float4 c) {
    c.x = fmaf(a, b.x, c.x);
    c.y = fmaf(a, b.y, c.y);
    c.z = fmaf(a, b.z, c.z);
    c.w = fmaf(a, b.w, c.w);
    return c;
}

__launch_bounds__(256, 4)
__global__ void ke_kernel(Params p) {
    // grid: 8 rel * 64 rowblocks * 2 negblocks = 1024 blocks
    const int bid = blockIdx.x;
    const int r   = bid & 7;
    const int rb  = (bid >> 3) & 63;
    const int nb  = bid >> 9;            // 0..1
    const int tid = threadIdx.x;
    const int tx  = tid & 15;            // rows tx*4 .. +3
    const int ty  = tid >> 4;            // negs ty*8 .. +7

    __shared__ float As[KC * BM];        // [k][row], ex = head+rvec fused
    __shared__ float Bs[KC * BN];        // [k][neg]

    const RelP rp = p.rel[r];

    // ---- staging assignments (fixed across k-chunks) ----
    // A: 320 float4/chunk. f=tid: row=tid&63, j=tid>>6; f=256+tid (tid<64): row=tid, j=4
    const int arow0 = tid & 63;
    const int aj0   = tid >> 6;
    const int h0    = p.batch_idxs[(rb * BM + arow0) * 8 + rp.hc];
    const float* aptr0 = rp.head + (size_t)h0 * EMBED + aj0 * 4;
    const float* rvp0  = p.rel_vecs + r * EMBED + aj0 * 4;
    const bool  doA1 = (tid < 64);
    const int   h1   = doA1 ? p.batch_idxs[(rb * BM + tid) * 8 + rp.hc] : 0;
    const float* aptr1 = rp.head + (size_t)h1 * EMBED + 16;
    const float* rvp1  = p.rel_vecs + r * EMBED + 16;

    // B: 640 float4/chunk. f=tid: neg=tid&127, j=tid>>7; f=tid+256: j+2;
    //    f=tid+512 (tid<128): neg=tid, j=4
    const int bneg0 = tid & 127;
    const int bj0   = tid >> 7;
    const int n0    = p.neg_idxs[r * NUM_NEG + nb * BN + bneg0];
    const float* bptr0 = rp.tail + (size_t)n0 * EMBED + bj0 * 4;
    const float* bptr1 = bptr0 + 8;
    const bool  doB2 = (tid < 128);
    const int   n2   = doB2 ? p.neg_idxs[r * NUM_NEG + nb * BN + tid] : 0;
    const float* bptr2 = rp.tail + (size_t)n2 * EMBED + 16;

    // 4 rows x 8 negs accumulator: c<i>0 = negs 0-3, c<i>1 = negs 4-7 of row i
    float4 c00 = {0,0,0,0}, c01 = {0,0,0,0};
    float4 c10 = {0,0,0,0}, c11 = {0,0,0,0};
    float4 c20 = {0,0,0,0}, c21 = {0,0,0,0};
    float4 c30 = {0,0,0,0}, c31 = {0,0,0,0};

#pragma unroll
    for (int kc = 0; kc < NCHUNK; ++kc) {
        const int k0 = kc * KC;

        // ---- stage A (ex = head + rvec), [k][row] ----
        {
            const float4 a  = *(const float4*)(aptr0 + k0);
            const float4 rv = *(const float4*)(rvp0 + k0);
            const int kb = aj0 * 4;
            As[(kb + 0) * BM + arow0] = a.x + rv.x;
            As[(kb + 1) * BM + arow0] = a.y + rv.y;
            As[(kb + 2) * BM + arow0] = a.z + rv.z;
            As[(kb + 3) * BM + arow0] = a.w + rv.w;
        }
        if (doA1) {
            const float4 a  = *(const float4*)(aptr1 + k0);
            const float4 rv = *(const float4*)(rvp1 + k0);
            As[16 * BM + tid] = a.x + rv.x;
            As[17 * BM + tid] = a.y + rv.y;
            As[18 * BM + tid] = a.z + rv.z;
            As[19 * BM + tid] = a.w + rv.w;
        }
        // ---- stage B, [k][neg] ----
        {
            const float4 b = *(const float4*)(bptr0 + k0);
            const int kb = bj0 * 4;
            Bs[(kb + 0) * BN + bneg0] = b.x;
            Bs[(kb + 1) * BN + bneg0] = b.y;
            Bs[(kb + 2) * BN + bneg0] = b.z;
            Bs[(kb + 3) * BN + bneg0] = b.w;
        }
        {
            const float4 b = *(const float4*)(bptr1 + k0);
            const int kb = bj0 * 4 + 8;
            Bs[(kb + 0) * BN + bneg0] = b.x;
            Bs[(kb + 1) * BN + bneg0] = b.y;
            Bs[(kb + 2) * BN + bneg0] = b.z;
            Bs[(kb + 3) * BN + bneg0] = b.w;
        }
        if (doB2) {
            const float4 b = *(const float4*)(bptr2 + k0);
            Bs[16 * BN + tid] = b.x;
            Bs[17 * BN + tid] = b.y;
            Bs[18 * BN + tid] = b.z;
            Bs[19 * BN + tid] = b.w;
        }
        __syncthreads();

        // ---- inner product over this k-chunk ----
#pragma unroll 4
        for (int k = 0; k < KC; ++k) {
            const float4 a  = *(const float4*)&As[k * BM + tx * 4];
            const float4 b0 = *(const float4*)&Bs[k * BN + ty * 8];
            const float4 b1 = *(const float4*)&Bs[k * BN + ty * 8 + 4];
            c00 = fma4(a.x, b0, c00); c01 = fma4(a.x, b1, c01);
            c10 = fma4(a.y, b0, c10); c11 = fma4(a.y, b1, c11);
            c20 = fma4(a.z, b0, c20); c21 = fma4(a.z, b1, c21);
            c30 = fma4(a.w, b0, c30); c31 = fma4(a.w, b1, c31);
        }
        __syncthreads();
    }

    // ---- epilogue: bias + softplus + sum ----
    float local = 0.0f;
    {
        const int g0 = rb * BM + tx * 4;
        const float bias0 = rp.bias[p.batch_idxs[(g0 + 0) * 8 + rp.tc]];
        const float bias1 = rp.bias[p.batch_idxs[(g0 + 1) * 8 + rp.tc]];
        const float bias2 = rp.bias[p.batch_idxs[(g0 + 2) * 8 + rp.tc]];
        const float bias3 = rp.bias[p.batch_idxs[(g0 + 3) * 8 + rp.tc]];
        local += softplus_f(c00.x + bias0) + softplus_f(c00.y + bias0)
               + softplus_f(c00.z + bias0) + softplus_f(c00.w + bias0)
               + softplus_f(c01.x + bias0) + softplus_f(c01.y + bias0)
               + softplus_f(c01.z + bias0) + softplus_f(c01.w + bias0);
        local += softplus_f(c10.x + bias1) + softplus_f(c10.y + bias1)
               + softplus_f(c10.z + bias1) + softplus_f(c10.w + bias1)
               + softplus_f(c11.x + bias1) + softplus_f(c11.y + bias1)
               + softplus_f(c11.z + bias1) + softplus_f(c11.w + bias1);
        local += softplus_f(c20.x + bias2) + softplus_f(c20.y + bias2)
               + softplus_f(c20.z + bias2) + softplus_f(c20.w + bias2)
               + softplus_f(c21.x + bias2) + softplus_f(c21.y + bias2)
               + softplus_f(c21.z + bias2) + softplus_f(c21.w + bias2);
        local += softplus_f(c30.x + bias3) + softplus_f(c30.y + bias3)
               + softplus_f(c30.z + bias3) + softplus_f(c30.w + bias3)
               + softplus_f(c31.x + bias3) + softplus_f(c31.y + bias3)
               + softplus_f(c31.z + bias3) + softplus_f(c31.w + bias3);
    }

    // ---- fused positive term: nb==0 blocks, one row per thread 0..63 ----
    if (nb == 0 && tid < BM) {
        const int row = rb * BM + tid;
        const int h = p.batch_idxs[row * 8 + rp.hc];
        const int t = p.batch_idxs[row * 8 + rp.tc];
        const float4* __restrict__ hv  = (const float4*)(rp.head + (size_t)h * EMBED);
        const float4* __restrict__ rv4 = (const float4*)(p.rel_vecs + r * EMBED);
        const float4* __restrict__ tv  = (const float4*)(rp.tail + (size_t)t * EMBED);
        float d0 = 0.f, d1 = 0.f, d2 = 0.f, d3 = 0.f;
#pragma unroll
        for (int j = 0; j < EMBED / 4; ++j) {
            const float4 a = hv[j];
            const float4 b = rv4[j];
            const float4 v = tv[j];
            d0 = fmaf(a.x + b.x, v.x, d0);
            d1 = fmaf(a.y + b.y, v.y, d1);
            d2 = fmaf(a.z + b.z, v.z, d2);
            d3 = fmaf(a.w + b.w, v.w, d3);
        }
        const float pos = ((d0 + d1) + (d2 + d3)) + rp.bias[t];
        local += softplus_f(-pos);
    }

    // ---- block reduction + one atomic ----
#pragma unroll
    for (int off = 32; off > 0; off >>= 1)
        local += __shfl_down(local, off, 64);
    __shared__ float wsum[4];
    const int wid  = tid >> 6;
    const int lane = tid & 63;
    if (lane == 0) wsum[wid] = local;
    __syncthreads();
    if (tid == 0) {
        const float s = (wsum[0] + wsum[1]) + (wsum[2] + wsum[3]);
        atomicAdd(p.out, s * (1.0f / BATCH));
    }
}

extern "C" void kernel_launch(void* const* d_in, const int* in_sizes, int n_in,
                              void* d_out, int out_size, void* d_ws, size_t ws_size,
                              hipStream_t stream) {
    const float* user  = (const float*)d_in[0];
    const float* prod  = (const float*)d_in[1];
    const float* word  = (const float*)d_in[2];
    const float* brand = (const float*)d_in[3];
    const float* cat   = (const float*)d_in[4];
    const float* rprod = (const float*)d_in[5];

    Params p;
    p.rel_vecs   = (const float*)d_in[6];
    p.batch_idxs = (const int*)d_in[15];
    p.neg_idxs   = (const int*)d_in[16];
    p.out        = (float*)d_out;

    p.rel[0] = {user, prod,  (const float*)d_in[7],  0, 1};  // purchase
    p.rel[1] = {user, word,  (const float*)d_in[8],  0, 2};  // mentions
    p.rel[2] = {prod, word,  (const float*)d_in[9],  1, 2};  // describe
    p.rel[3] = {prod, brand, (const float*)d_in[10], 1, 3};  // produced
    p.rel[4] = {prod, cat,   (const float*)d_in[11], 1, 4};  // belongs
    p.rel[5] = {prod, rprod, (const float*)d_in[12], 1, 5};  // also_bought
    p.rel[6] = {prod, rprod, (const float*)d_in[13], 1, 6};  // also_viewed
    p.rel[7] = {prod, rprod, (const float*)d_in[14], 1, 7};  // together

    hipMemsetAsync(d_out, 0, sizeof(float), stream);
    ke_kernel<<<1024, 256, 0, stream>>>(p);
}

// Round 7
// 155.229 us; speedup vs baseline: 1.0921x; 1.0921x over previous
//
#include <hip/hip_runtime.h>

// KnowledgeEmbedding loss via bf16 MFMA GEMMs.
// Per relation r: score(row,neg) = dot(head[h_row]+rvec_r, tail[neg]) + bias[t_row]
// loss = (1/B) * sum_rel [ sum_row softplus(-pos_row) + sum_{row,neg} softplus(score) ]
//
// Structure: block = 128 rows x 128 negs, K=100 padded to 128 (4 MFMA k-steps of
// 16x16x32 bf16). Bias is folded into the GEMM: A[row][k=100]=bias[t_row],
// B[neg][k=100]=1.0, zeros elsewhere in the pad -> epilogue is a pure
// layout-agnostic softplus-sum (permutation invariant).
// Staging: one phase, one barrier; thread t owns one full row (contiguous
// 400 B), converts fp32->bf16 (RNE), writes row-major LDS (pitch 256 B).
// MFMA frag reads: lane (i=lane&15, q=lane>>4) reads row i, shorts q*8+s*32
// (contiguous 16 B, b128).
// HISTORY: R1-R6 VALU path plateaued at 43.5 us, duration invariant to
// occupancy -> gather-path bound (~1.8 TB/s on 78 MB staged). This cuts
// staged bytes to 52 MB and moves FMA to the MFMA pipe.

#define EMBED   100
#define BATCH   4096
#define NUM_NEG 256
#define BM      128
#define BN      128
#define PITCH   128   // shorts per LDS row (= 256 B, K padded to 128)

typedef __attribute__((ext_vector_type(8))) short s8;
typedef __attribute__((ext_vector_type(4))) short s4;
typedef __attribute__((ext_vector_type(4))) float f4;

struct RelP {
    const float* head;
    const float* tail;
    const float* bias;
    int hc, tc;
};

struct Params {
    RelP rel[8];
    const float* rel_vecs;
    const int*   batch_idxs;
    const int*   neg_idxs;
    float*       out;
};

__device__ __forceinline__ float softplus_f(float x) {
    float e = __expf(-fabsf(x));
    return fmaxf(x, 0.0f) + __logf(1.0f + e);
}

__device__ __forceinline__ unsigned short bf16_rne(float f) {
    unsigned u = __float_as_uint(f);
    u += 0x7FFFu + ((u >> 16) & 1u);
    return (unsigned short)(u >> 16);
}

__launch_bounds__(256, 2)
__global__ void ke_kernel(Params p) {
    // grid: 8 rel * 32 rowblocks * 2 negblocks = 512
    const int bid = blockIdx.x;
    const int r   = bid & 7;
    const int rb  = (bid >> 3) & 31;
    const int nb  = bid >> 8;            // 0..1
    const int tid = threadIdx.x;

    __shared__ __align__(16) short As[BM * PITCH];   // [row][k] bf16, k100=bias
    __shared__ __align__(16) short Bs[BN * PITCH];   // [neg][k] bf16, k100=1.0

    const RelP rp = p.rel[r];

    // ---- staging: thread t owns one full row ----
    {
        const bool isA = tid < BM;
        const float* src;
        unsigned short extra;            // value at k=100
        if (isA) {
            const int grow = rb * BM + tid;
            const int h  = p.batch_idxs[grow * 8 + rp.hc];
            const int ti = p.batch_idxs[grow * 8 + rp.tc];
            src   = rp.head + (size_t)h * EMBED;
            extra = bf16_rne(rp.bias[ti]);
        } else {
            const int n = p.neg_idxs[r * NUM_NEG + nb * BN + (tid - BM)];
            src   = rp.tail + (size_t)n * EMBED;
            extra = 0x3F80;              // bf16(1.0)
        }
        short* dst = isA ? (As + tid * PITCH) : (Bs + (tid - BM) * PITCH);
        const float4* s4p = (const float4*)src;
        const float4* rv4 = (const float4*)(p.rel_vecs + r * EMBED);

#pragma unroll
        for (int j = 0; j < 12; ++j) {
            float4 f0 = s4p[2 * j];
            float4 f1 = s4p[2 * j + 1];
            if (isA) {
                const float4 a = rv4[2 * j];
                const float4 b = rv4[2 * j + 1];
                f0.x += a.x; f0.y += a.y; f0.z += a.z; f0.w += a.w;
                f1.x += b.x; f1.y += b.y; f1.z += b.z; f1.w += b.w;
            }
            s8 v = { (short)bf16_rne(f0.x), (short)bf16_rne(f0.y),
                     (short)bf16_rne(f0.z), (short)bf16_rne(f0.w),
                     (short)bf16_rne(f1.x), (short)bf16_rne(f1.y),
                     (short)bf16_rne(f1.z), (short)bf16_rne(f1.w) };
            *(s8*)(dst + 8 * j) = v;
        }
        {   // floats 96..99
            float4 f = s4p[24];
            if (isA) {
                const float4 a = rv4[24];
                f.x += a.x; f.y += a.y; f.z += a.z; f.w += a.w;
            }
            s4 v = { (short)bf16_rne(f.x), (short)bf16_rne(f.y),
                     (short)bf16_rne(f.z), (short)bf16_rne(f.w) };
            *(s4*)(dst + 96) = v;
        }
        {   // k=100 (bias / 1.0), zeros k=101..127
            s4 v = { (short)extra, 0, 0, 0 };
            *(s4*)(dst + 100) = v;
            s4 z = { 0, 0, 0, 0 };
#pragma unroll
            for (int j = 0; j < 6; ++j)
                *(s4*)(dst + 104 + 4 * j) = z;
        }
    }
    __syncthreads();

    // ---- MFMA compute: wave tile 64x64 (4x4 tiles of 16x16x32, 4 k-steps) ----
    const int wave = tid >> 6;
    const int lane = tid & 63;
    const int li   = lane & 15;
    const int q    = lane >> 4;
    const int wm   = wave >> 1;          // 0..1 row half
    const int wn   = wave & 1;           // 0..1 neg half

    f4 acc[4][4];
#pragma unroll
    for (int i = 0; i < 4; ++i)
#pragma unroll
        for (int j = 0; j < 4; ++j)
            acc[i][j] = (f4){0.f, 0.f, 0.f, 0.f};

    const short* Abase = As + (wm * 64 + li) * PITCH + q * 8;
    const short* Bbase = Bs + (wn * 64 + li) * PITCH + q * 8;

#pragma unroll
    for (int s = 0; s < 4; ++s) {
        const s8 a0 = *(const s8*)(Abase +  0 * PITCH + s * 32);
        const s8 a1 = *(const s8*)(Abase + 16 * PITCH + s * 32);
        const s8 a2 = *(const s8*)(Abase + 32 * PITCH + s * 32);
        const s8 a3 = *(const s8*)(Abase + 48 * PITCH + s * 32);
        const s8 b0 = *(const s8*)(Bbase +  0 * PITCH + s * 32);
        const s8 b1 = *(const s8*)(Bbase + 16 * PITCH + s * 32);
        const s8 b2 = *(const s8*)(Bbase + 32 * PITCH + s * 32);
        const s8 b3 = *(const s8*)(Bbase + 48 * PITCH + s * 32);
        acc[0][0] = __builtin_amdgcn_mfma_f32_16x16x32_bf16(a0, b0, acc[0][0], 0, 0, 0);
        acc[0][1] = __builtin_amdgcn_mfma_f32_16x16x32_bf16(a0, b1, acc[0][1], 0, 0, 0);
        acc[0][2] = __builtin_amdgcn_mfma_f32_16x16x32_bf16(a0, b2, acc[0][2], 0, 0, 0);
        acc[0][3] = __builtin_amdgcn_mfma_f32_16x16x32_bf16(a0, b3, acc[0][3], 0, 0, 0);
        acc[1][0] = __builtin_amdgcn_mfma_f32_16x16x32_bf16(a1, b0, acc[1][0], 0, 0, 0);
        acc[1][1] = __builtin_amdgcn_mfma_f32_16x16x32_bf16(a1, b1, acc[1][1], 0, 0, 0);
        acc[1][2] = __builtin_amdgcn_mfma_f32_16x16x32_bf16(a1, b2, acc[1][2], 0, 0, 0);
        acc[1][3] = __builtin_amdgcn_mfma_f32_16x16x32_bf16(a1, b3, acc[1][3], 0, 0, 0);
        acc[2][0] = __builtin_amdgcn_mfma_f32_16x16x32_bf16(a2, b0, acc[2][0], 0, 0, 0);
        acc[2][1] = __builtin_amdgcn_mfma_f32_16x16x32_bf16(a2, b1, acc[2][1], 0, 0, 0);
        acc[2][2] = __builtin_amdgcn_mfma_f32_16x16x32_bf16(a2, b2, acc[2][2], 0, 0, 0);
        acc[2][3] = __builtin_amdgcn_mfma_f32_16x16x32_bf16(a2, b3, acc[2][3], 0, 0, 0);
        acc[3][0] = __builtin_amdgcn_mfma_f32_16x16x32_bf16(a3, b0, acc[3][0], 0, 0, 0);
        acc[3][1] = __builtin_amdgcn_mfma_f32_16x16x32_bf16(a3, b1, acc[3][1], 0, 0, 0);
        acc[3][2] = __builtin_amdgcn_mfma_f32_16x16x32_bf16(a3, b2, acc[3][2], 0, 0, 0);
        acc[3][3] = __builtin_amdgcn_mfma_f32_16x16x32_bf16(a3, b3, acc[3][3], 0, 0, 0);
    }

    // ---- epilogue: softplus-sum (bias already inside acc; permutation-invariant) ----
    float local = 0.0f;
#pragma unroll
    for (int i = 0; i < 4; ++i)
#pragma unroll
        for (int j = 0; j < 4; ++j) {
            local += softplus_f(acc[i][j].x);
            local += softplus_f(acc[i][j].y);
            local += softplus_f(acc[i][j].z);
            local += softplus_f(acc[i][j].w);
        }

    // ---- fused positive term (fp32): nb==0 blocks, one row per thread 0..127 ----
    if (nb == 0 && tid < BM) {
        const int row = rb * BM + tid;
        const int h = p.batch_idxs[row * 8 + rp.hc];
        const int t = p.batch_idxs[row * 8 + rp.tc];
        const float4* __restrict__ hv  = (const float4*)(rp.head + (size_t)h * EMBED);
        const float4* __restrict__ rv4 = (const float4*)(p.rel_vecs + r * EMBED);
        const float4* __restrict__ tv  = (const float4*)(rp.tail + (size_t)t * EMBED);
        float d0 = 0.f, d1 = 0.f, d2 = 0.f, d3 = 0.f;
#pragma unroll
        for (int j = 0; j < EMBED / 4; ++j) {
            const float4 a = hv[j];
            const float4 b = rv4[j];
            const float4 v = tv[j];
            d0 = fmaf(a.x + b.x, v.x, d0);
            d1 = fmaf(a.y + b.y, v.y, d1);
            d2 = fmaf(a.z + b.z, v.z, d2);
            d3 = fmaf(a.w + b.w, v.w, d3);
        }
        const float pos = ((d0 + d1) + (d2 + d3)) + rp.bias[t];
        local += softplus_f(-pos);
    }

    // ---- reduction: wave shuffle, then LDS (aliased over As after barrier) ----
#pragma unroll
    for (int off = 32; off > 0; off >>= 1)
        local += __shfl_down(local, off, 64);

    __syncthreads();                     // all As reads done -> safe to alias
    float* wsum = (float*)As;
    if (lane == 0) wsum[wave] = local;
    __syncthreads();
    if (tid == 0) {
        const float s = (wsum[0] + wsum[1]) + (wsum[2] + wsum[3]);
        atomicAdd(p.out, s * (1.0f / BATCH));
    }
}

extern "C" void kernel_launch(void* const* d_in, const int* in_sizes, int n_in,
                              void* d_out, int out_size, void* d_ws, size_t ws_size,
                              hipStream_t stream) {
    const float* user  = (const float*)d_in[0];
    const float* prod  = (const float*)d_in[1];
    const float* word  = (const float*)d_in[2];
    const float* brand = (const float*)d_in[3];
    const float* cat   = (const float*)d_in[4];
    const float* rprod = (const float*)d_in[5];

    Params p;
    p.rel_vecs   = (const float*)d_in[6];
    p.batch_idxs = (const int*)d_in[15];
    p.neg_idxs   = (const int*)d_in[16];
    p.out        = (float*)d_out;

    p.rel[0] = {user, prod,  (const float*)d_in[7],  0, 1};  // purchase
    p.rel[1] = {user, word,  (const float*)d_in[8],  0, 2};  // mentions
    p.rel[2] = {prod, word,  (const float*)d_in[9],  1, 2};  // describe
    p.rel[3] = {prod, brand, (const float*)d_in[10], 1, 3};  // produced
    p.rel[4] = {prod, cat,   (const float*)d_in[11], 1, 4};  // belongs
    p.rel[5] = {prod, rprod, (const float*)d_in[12], 1, 5};  // also_bought
    p.rel[6] = {prod, rprod, (const float*)d_in[13], 1, 6};  // also_viewed
    p.rel[7] = {prod, rprod, (const float*)d_in[14], 1, 7};  // together

    hipMemsetAsync(d_out, 0, sizeof(float), stream);
    ke_kernel<<<512, 256, 0, stream>>>(p);
}